// Round 1
// baseline (10046.236 us; speedup 1.0000x reference)
//
#include <hip/hip_runtime.h>
#include <hip/hip_fp16.h>

#define T_LEN 4096
#define START_TAG 14
#define STOP_TAG 15
#define NEG_VAL -10000.0f

typedef unsigned int u32;
typedef unsigned short u16;
typedef unsigned long long u64;

typedef _Float16 h2vec __attribute__((ext_vector_type(2)));

// ---------- ws layout (bytes) ----------
#define GX_OFF      0u              // __half [4096][2048]  (dir*1024 + gate*256 + d)
#define OUT_OFF     16777216u       // float  [4096][512]   (concat hf, hb)
#define LOGITS_OFF  25165824u       // float  [4096]
#define ALPHAS_OFF  25182208u       // float  [4096]
#define FEATS_OFF   25198592u       // float  [4096][16]
#define HX_OFF      25460736u       // u64    [4 wg][2 parity][128]

__device__ __forceinline__ float dot2h(u32 a, u32 b, float acc) {
#if __has_builtin(__builtin_amdgcn_fdot2)
  return __builtin_amdgcn_fdot2(__builtin_bit_cast(h2vec, a),
                                __builtin_bit_cast(h2vec, b), acc, false);
#else
  h2vec x = __builtin_bit_cast(h2vec, a);
  h2vec y = __builtin_bit_cast(h2vec, b);
  return acc + (float)x[0]*(float)y[0] + (float)x[1]*(float)y[1];
#endif
}

__device__ __forceinline__ u32 pack2h(float a, float b) {
  return (u32)__half_as_ushort(__float2half(a)) |
         ((u32)__half_as_ushort(__float2half(b)) << 16);
}

__device__ __forceinline__ float sigm(float x) {
  return __builtin_amdgcn_rcpf(1.f + __expf(-x));
}
__device__ __forceinline__ float tanh_fast(float x) {
  float e = __expf(-2.f * fabsf(x));
  float r = (1.f - e) * __builtin_amdgcn_rcpf(1.f + e);
  return copysignf(r, x);
}

// ---------------------------------------------------------------------------
__global__ void prep_kernel(float* logits, u64* hx) {
  const int i = threadIdx.x + blockIdx.x * 1024;
  if (i < 4096) logits[i] = 0.f;
  if (i < 1024) hx[i] = 0ull;
}

// ---------------------------------------------------------------------------
// Gx[t][R] = emb[sentence[t]] . W_R + bih_R + bhh_R   (R = dir*1024 + row)
// block: 32 t x 32 rows, 256 threads.
__global__ __launch_bounds__(256) void gx_kernel(
    const int* __restrict__ sentence, const float* __restrict__ emb,
    const float* __restrict__ Wih_f, const float* __restrict__ Wih_b,
    const float* __restrict__ bih_f, const float* __restrict__ bhh_f,
    const float* __restrict__ bih_b, const float* __restrict__ bhh_b,
    __half* __restrict__ Gx)
{
  __shared__ float ws[32][260];
  const int r0 = blockIdx.x * 32;
  const int t0 = blockIdx.y * 32;
  const int tid = threadIdx.x;
  {
    const int c4 = (tid & 63) * 4;
    const int rA = tid >> 6;
    #pragma unroll
    for (int p = 0; p < 8; ++p) {
      const int rr = rA + p * 4;
      const int R = r0 + rr;
      const float* src = (R < 1024) ? (Wih_f + (size_t)R * 256 + c4)
                                    : (Wih_b + (size_t)(R - 1024) * 256 + c4);
      *(float4*)&ws[rr][c4] = *(const float4*)src;
    }
  }
  __syncthreads();
  const int ttb = tid >> 4, rgb = tid & 15;
  const int s0r = sentence[t0 + ttb];
  const int s1r = sentence[t0 + ttb + 16];
  const float* x0p = emb + (size_t)s0r * 256;
  const float* x1p = emb + (size_t)s1r * 256;
  float acc00 = 0, acc01 = 0, acc10 = 0, acc11 = 0;
  #pragma unroll 4
  for (int c4 = 0; c4 < 256; c4 += 4) {
    float4 x0 = *(const float4*)(x0p + c4);
    float4 x1 = *(const float4*)(x1p + c4);
    float4 w0 = *(const float4*)&ws[rgb][c4];
    float4 w1 = *(const float4*)&ws[rgb + 16][c4];
    acc00 += x0.x*w0.x + x0.y*w0.y + x0.z*w0.z + x0.w*w0.w;
    acc01 += x0.x*w1.x + x0.y*w1.y + x0.z*w1.z + x0.w*w1.w;
    acc10 += x1.x*w0.x + x1.y*w0.y + x1.z*w0.z + x1.w*w0.w;
    acc11 += x1.x*w1.x + x1.y*w1.y + x1.z*w1.z + x1.w*w1.w;
  }
  #pragma unroll
  for (int ri = 0; ri < 2; ++ri) {
    const int R = r0 + rgb + ri * 16;
    const int dir = R >> 10, grow = R & 1023;
    const float bias = dir ? (bih_b[grow] + bhh_b[grow])
                           : (bih_f[grow] + bhh_f[grow]);
    const float a0 = ri ? acc01 : acc00;
    const float a1 = ri ? acc11 : acc10;
    Gx[(size_t)(t0 + ttb) * 2048 + R]      = __float2half(a0 + bias);
    Gx[(size_t)(t0 + ttb + 16) * 2048 + R] = __float2half(a1 + bias);
  }
}

// ---------------------------------------------------------------------------
// Recurrence: 4 WGs (dir 0/1 x half 0/1), 1024 threads. Whh as fp16 in VGPRs.
// Thread tid: row lr=tid>>1 (gate=lr>>7, j=lr&127), col-half ch=tid&1.
__global__ __launch_bounds__(1024) void lstm_kernel(
    const float* __restrict__ Whh_f, const float* __restrict__ Whh_b,
    const float* __restrict__ h0, const float* __restrict__ c0,
    const __half* __restrict__ Gx, float* __restrict__ out_lstm,
    u64* __restrict__ hx)
{
  const int wg = blockIdx.x;
  const int dir = wg >> 1, kk = wg & 1;
  const int tid = threadIdx.x;
  const int lr = tid >> 1, ch = tid & 1;
  const int gate = lr >> 7, jj = lr & 127;
  const int grow = gate * 256 + kk * 128 + jj;
  const float* Whh = dir ? Whh_b : Whh_f;

  __shared__ __align__(16) u16 hbuf[256];
  __shared__ float gates[512];

  u32 w[64];
  {
    const float* wrow = Whh + (size_t)grow * 256 + ch * 128;
    #pragma unroll
    for (int i = 0; i < 32; ++i) {
      float4 f = ((const float4*)wrow)[i];
      w[2*i]   = pack2h(f.x, f.y);
      w[2*i+1] = pack2h(f.z, f.w);
    }
  }
  if (tid < 256) hbuf[tid] = __half_as_ushort(__float2half(h0[dir * 256 + tid]));
  float creg = 0.f;
  u16 p0 = 0, p1 = 0, p2 = 0, p3 = 0;
  if (tid < 128) {
    creg = c0[dir * 256 + kk * 128 + tid];
    const int t0 = dir ? (T_LEN - 1) : 0;
    const u16* g = (const u16*)Gx + (size_t)t0 * 2048 + dir * 1024 + kk * 128 + tid;
    p0 = g[0]; p1 = g[256]; p2 = g[512]; p3 = g[768];
  }
  __syncthreads();

  const uint4* hp4 = (const uint4*)hbuf;
  for (int s = 0; s < T_LEN; ++s) {
    const int t = dir ? (T_LEN - 1 - s) : s;
    // phase A: 128-col partial dot (fp16 dot2, fp32 accum)
    float a0 = 0.f, a1 = 0.f;
    #pragma unroll
    for (int m = 0; m < 16; m += 2) {
      uint4 ha = hp4[ch * 16 + m];
      uint4 hb = hp4[ch * 16 + m + 1];
      a0 = dot2h(w[4*m+0], ha.x, a0);
      a0 = dot2h(w[4*m+1], ha.y, a0);
      a0 = dot2h(w[4*m+2], ha.z, a0);
      a0 = dot2h(w[4*m+3], ha.w, a0);
      a1 = dot2h(w[4*m+4], hb.x, a1);
      a1 = dot2h(w[4*m+5], hb.y, a1);
      a1 = dot2h(w[4*m+6], hb.z, a1);
      a1 = dot2h(w[4*m+7], hb.w, a1);
    }
    float asum = a0 + a1;
    asum += __shfl_xor(asum, 1);
    if (ch == 0) gates[lr] = asum;
    __syncthreads();
    if (tid < 128) {
      // phase C: gates -> (c,h) for local d slice
      float gi = gates[tid]       + __half2float(__ushort_as_half(p0));
      float gf = gates[128 + tid] + __half2float(__ushort_as_half(p1));
      float gg = gates[256 + tid] + __half2float(__ushort_as_half(p2));
      float go = gates[384 + tid] + __half2float(__ushort_as_half(p3));
      if (s + 1 < T_LEN) {   // prefetch next step's Gx (raw bits; cvt next iter)
        const int tn = dir ? (T_LEN - 2 - s) : (s + 1);
        const u16* g = (const u16*)Gx + (size_t)tn * 2048 + dir * 1024 + kk * 128 + tid;
        p0 = g[0]; p1 = g[256]; p2 = g[512]; p3 = g[768];
      }
      const float iv = sigm(gi);
      const float fvv = sigm(gf);
      const float gv = tanh_fast(gg);
      const float ov = sigm(go);
      creg = fvv * creg + iv * gv;
      const float h = ov * tanh_fast(creg);
      out_lstm[(size_t)t * 512 + dir * 256 + kk * 128 + tid] = h;
      const u16 hb16 = __half_as_ushort(__float2half(h));
      hbuf[kk * 128 + tid] = hb16;
      // post {gen, h} to partner; parity double-buffer kills overwrite race
      __hip_atomic_store(&hx[(((wg << 1) + (s & 1)) << 7) + tid],
                         ((u64)(u32)(s + 1) << 32) | (u64)hb16,
                         __ATOMIC_RELAXED, __HIP_MEMORY_SCOPE_AGENT);
    } else if (tid < 256) {
      // phase D: pull partner's half
      const int j2 = tid - 128;
      u64 v; int guard = 0;
      do {
        v = __hip_atomic_load(&hx[((((wg ^ 1) << 1) + (s & 1)) << 7) + j2],
                              __ATOMIC_RELAXED, __HIP_MEMORY_SCOPE_AGENT);
      } while ((u32)(v >> 32) != (u32)(s + 1) && ++guard < (1 << 27));
      hbuf[((kk ^ 1) << 7) + j2] = (u16)(v & 0xFFFFu);
    }
    __syncthreads();
  }
}

// ---------------------------------------------------------------------------
// logits[t] = sum_c tanh(out[t] @ w_omega)[c] * u_omega[c]
// block: 32 t x 32 c, K=512 in 4 chunks of 128.
__global__ __launch_bounds__(256) void attn_kernel(
    const float* __restrict__ out_lstm, const float* __restrict__ w_omega,
    const float* __restrict__ u_omega, float* __restrict__ logits)
{
  __shared__ float bst[32][132];   // [c][k-chunk], transposed w_omega
  const int c0 = blockIdx.x * 32;
  const int t0 = blockIdx.y * 32;
  const int tid = threadIdx.x;
  const int ttb = tid >> 4, cgb = tid & 15;
  const float* a0p = out_lstm + (size_t)(t0 + ttb) * 512;
  const float* a1p = out_lstm + (size_t)(t0 + ttb + 16) * 512;
  float acc00 = 0, acc01 = 0, acc10 = 0, acc11 = 0;
  for (int kh = 0; kh < 4; ++kh) {
    __syncthreads();
    {
      const int cc = tid & 31;
      const int kA = tid >> 5;
      #pragma unroll
      for (int p = 0; p < 16; ++p) {
        const int kkx = kA + p * 8;
        bst[cc][kkx] = w_omega[(size_t)(kh * 128 + kkx) * 512 + c0 + cc];
      }
    }
    __syncthreads();
    #pragma unroll 4
    for (int k4 = 0; k4 < 128; k4 += 4) {
      float4 a0 = *(const float4*)(a0p + kh * 128 + k4);
      float4 a1 = *(const float4*)(a1p + kh * 128 + k4);
      float4 b0 = *(const float4*)&bst[cgb][k4];
      float4 b1 = *(const float4*)&bst[cgb + 16][k4];
      acc00 += a0.x*b0.x + a0.y*b0.y + a0.z*b0.z + a0.w*b0.w;
      acc01 += a0.x*b1.x + a0.y*b1.y + a0.z*b1.z + a0.w*b1.w;
      acc10 += a1.x*b0.x + a1.y*b0.y + a1.z*b0.z + a1.w*b0.w;
      acc11 += a1.x*b1.x + a1.y*b1.y + a1.z*b1.z + a1.w*b1.w;
    }
  }
  const float u0 = u_omega[c0 + cgb], u1 = u_omega[c0 + 16 + cgb];
  float s0 = tanh_fast(acc00) * u0 + tanh_fast(acc01) * u1;
  float s1 = tanh_fast(acc10) * u0 + tanh_fast(acc11) * u1;
  #pragma unroll
  for (int msk = 1; msk < 16; msk <<= 1) {
    s0 += __shfl_xor(s0, msk);
    s1 += __shfl_xor(s1, msk);
  }
  if (cgb == 0) {
    atomicAdd(&logits[t0 + ttb], s0);
    atomicAdd(&logits[t0 + ttb + 16], s1);
  }
}

// ---------------------------------------------------------------------------
__global__ __launch_bounds__(1024) void softmax_kernel(
    const float* __restrict__ logits, float* __restrict__ alphas)
{
  __shared__ float red[1024];
  const int tid = threadIdx.x;
  float l0 = logits[tid], l1 = logits[1024 + tid];
  float l2 = logits[2048 + tid], l3 = logits[3072 + tid];
  red[tid] = fmaxf(fmaxf(l0, l1), fmaxf(l2, l3));
  __syncthreads();
  for (int s = 512; s > 0; s >>= 1) {
    if (tid < s) red[tid] = fmaxf(red[tid], red[tid + s]);
    __syncthreads();
  }
  const float gm = red[0];
  __syncthreads();
  float e0 = __expf(l0 - gm), e1 = __expf(l1 - gm);
  float e2 = __expf(l2 - gm), e3 = __expf(l3 - gm);
  red[tid] = e0 + e1 + e2 + e3;
  __syncthreads();
  for (int s = 512; s > 0; s >>= 1) {
    if (tid < s) red[tid] += red[tid + s];
    __syncthreads();
  }
  const float inv = 1.0f / red[0];
  alphas[tid] = e0 * inv; alphas[1024 + tid] = e1 * inv;
  alphas[2048 + tid] = e2 * inv; alphas[3072 + tid] = e3 * inv;
}

// ---------------------------------------------------------------------------
// feats[t][tag] = alpha[t] * (out[t] . W_tag[tag]) + b_tag[tag]
__global__ __launch_bounds__(256) void feats_kernel(
    const float* __restrict__ out_lstm, const float* __restrict__ W_tag,
    const float* __restrict__ b_tag, const float* __restrict__ alphas,
    float* __restrict__ feats)
{
  __shared__ float wt[16][516];
  const int t0 = blockIdx.x * 16;
  const int tid = threadIdx.x;
  {
    const int k4 = (tid & 127) * 4;
    const int gA = tid >> 7;
    #pragma unroll
    for (int p = 0; p < 8; ++p) {
      const int tg = gA + p * 2;
      *(float4*)&wt[tg][k4] = *(const float4*)(W_tag + (size_t)tg * 512 + k4);
    }
  }
  __syncthreads();
  const int tt = tid >> 4, tg = tid & 15;
  const float* ap = out_lstm + (size_t)(t0 + tt) * 512;
  float acc = 0.f;
  #pragma unroll 4
  for (int k4 = 0; k4 < 512; k4 += 4) {
    float4 a = *(const float4*)(ap + k4);
    float4 b = *(const float4*)&wt[tg][k4];
    acc += a.x*b.x + a.y*b.y + a.z*b.z + a.w*b.w;
  }
  feats[(size_t)(t0 + tt) * 16 + tg] = acc * alphas[t0 + tt] + b_tag[tg];
}

// ---------------------------------------------------------------------------
// Sequential Viterbi, one wave. lane l: n=l&15, pg=l>>4 (4 prev each).
// bp nibble-packed in LDS (32KB). Backtrack by lane 0.
__global__ __launch_bounds__(64) void viterbi_kernel(
    const float* __restrict__ feats, const float* __restrict__ trans,
    float* __restrict__ d_out)
{
  __shared__ __align__(16) float fv[16];
  __shared__ u32 bpw[T_LEN * 2];
  const int l = threadIdx.x;
  const int n = l & 15, pg = l >> 4;
  const float4 tr4 = *(const float4*)(trans + n * 16 + pg * 4);
  if (l < 16) fv[l] = (l == START_TAG) ? 0.f : NEG_VAL;
  float fcur = (l < 16) ? feats[l] : 0.f;
  __syncthreads();
  for (int t = 0; t < T_LEN; ++t) {
    float4 f4 = *(const float4*)&fv[pg * 4];
    float m = f4.x + tr4.x; int mi = pg * 4;
    float c;
    c = f4.y + tr4.y; if (c > m) { m = c; mi = pg * 4 + 1; }
    c = f4.z + tr4.z; if (c > m) { m = c; mi = pg * 4 + 2; }
    c = f4.w + tr4.w; if (c > m) { m = c; mi = pg * 4 + 3; }
    float om; int omi;
    om = __shfl_xor(m, 16); omi = __shfl_xor(mi, 16);
    if (om > m || (om == m && omi < mi)) { m = om; mi = omi; }
    om = __shfl_xor(m, 32); omi = __shfl_xor(mi, 32);
    if (om > m || (om == m && omi < mi)) { m = om; mi = omi; }
    float fnext = 0.f;
    if (l < 16 && t + 1 < T_LEN) fnext = feats[(t + 1) * 16 + l];
    u32 v = (l < 16) ? ((u32)mi << ((n & 7) * 4)) : 0u;
    v |= __shfl_xor(v, 1);
    v |= __shfl_xor(v, 2);
    v |= __shfl_xor(v, 4);
    if (l == 0) bpw[t * 2] = v;
    if (l == 8) bpw[t * 2 + 1] = v;
    if (l < 16) fv[l] = m + fcur;
    fcur = fnext;
    __syncthreads();
  }
  if (l < 16) {
    float m = fv[l] + trans[STOP_TAG * 16 + l];
    int mi = l;
    #pragma unroll
    for (int msk = 1; msk < 16; msk <<= 1) {
      float om = __shfl_xor(m, msk); int omi = __shfl_xor(mi, msk);
      if (om > m || (om == m && omi < mi)) { m = om; mi = omi; }
    }
    if (l == 0) {
      d_out[0] = m;
      int cur = mi;
      for (int t = T_LEN - 1; t >= 0; --t) {
        d_out[1 + t] = (float)cur;
        const u32 word = bpw[t * 2 + (cur >> 3)];
        cur = (int)((word >> ((cur & 7) * 4)) & 15u);
      }
    }
  }
}

// ---------------------------------------------------------------------------
extern "C" void kernel_launch(void* const* d_in, const int* in_sizes, int n_in,
                              void* d_out, int out_size, void* d_ws, size_t ws_size,
                              hipStream_t stream)
{
  const int*   sentence = (const int*)  d_in[0];
  const float* emb      = (const float*)d_in[1];
  const float* Wih_f    = (const float*)d_in[2];
  const float* Whh_f    = (const float*)d_in[3];
  const float* bih_f    = (const float*)d_in[4];
  const float* bhh_f    = (const float*)d_in[5];
  const float* Wih_b    = (const float*)d_in[6];
  const float* Whh_b    = (const float*)d_in[7];
  const float* bih_b    = (const float*)d_in[8];
  const float* bhh_b    = (const float*)d_in[9];
  const float* h0       = (const float*)d_in[10];
  const float* c0       = (const float*)d_in[11];
  const float* w_omega  = (const float*)d_in[12];
  const float* u_omega  = (const float*)d_in[13];
  const float* W_tag    = (const float*)d_in[14];
  const float* b_tag    = (const float*)d_in[15];
  const float* trans    = (const float*)d_in[16];

  char* ws = (char*)d_ws;
  __half* Gx      = (__half*)(ws + GX_OFF);
  float* out_lstm = (float*)(ws + OUT_OFF);
  float* logits   = (float*)(ws + LOGITS_OFF);
  float* alphas   = (float*)(ws + ALPHAS_OFF);
  float* feats    = (float*)(ws + FEATS_OFF);
  u64*   hx       = (u64*)  (ws + HX_OFF);
  float* out      = (float*)d_out;

  hipLaunchKernelGGL(prep_kernel, dim3(4), dim3(1024), 0, stream, logits, hx);
  hipLaunchKernelGGL(gx_kernel, dim3(64, 128), dim3(256), 0, stream,
                     sentence, emb, Wih_f, Wih_b, bih_f, bhh_f, bih_b, bhh_b, Gx);
  hipLaunchKernelGGL(lstm_kernel, dim3(4), dim3(1024), 0, stream,
                     Whh_f, Whh_b, h0, c0, Gx, out_lstm, hx);
  hipLaunchKernelGGL(attn_kernel, dim3(16, 128), dim3(256), 0, stream,
                     out_lstm, w_omega, u_omega, logits);
  hipLaunchKernelGGL(softmax_kernel, dim3(1), dim3(1024), 0, stream, logits, alphas);
  hipLaunchKernelGGL(feats_kernel, dim3(256), dim3(256), 0, stream,
                     out_lstm, W_tag, b_tag, alphas, feats);
  hipLaunchKernelGGL(viterbi_kernel, dim3(1), dim3(64), 0, stream, feats, trans, out);
}

// Round 2
// 7336.088 us; speedup vs baseline: 1.3694x; 1.3694x over previous
//
#include <hip/hip_runtime.h>
#include <hip/hip_fp16.h>

#define T_LEN 4096
#define START_TAG 14
#define STOP_TAG 15
#define NEG_VAL -10000.0f

typedef unsigned int u32;
typedef unsigned short u16;
typedef unsigned long long u64;

// ---------- ws layout (bytes) ----------
#define GX_OFF      0u              // __half [4096][2048]  (dir*1024 + gate*256 + d)
#define OUT_OFF     16777216u       // float  [4096][512]   (concat hf, hb)
#define LOGITS_OFF  25165824u       // float  [4096]
#define ALPHAS_OFF  25182208u       // float  [4096]
#define FEATS_OFF   25198592u       // float  [4096][16]

__device__ __forceinline__ int sdot4(u32 a, u32 b, int c) {
#if __has_builtin(__builtin_amdgcn_sdot4)
  return __builtin_amdgcn_sdot4((int)a, (int)b, c, false);
#else
  c += (int)(signed char)(a & 0xff)         * (int)(signed char)(b & 0xff);
  c += (int)(signed char)((a >> 8) & 0xff)  * (int)(signed char)((b >> 8) & 0xff);
  c += (int)(signed char)((a >> 16) & 0xff) * (int)(signed char)((b >> 16) & 0xff);
  c += (int)(signed char)((a >> 24) & 0xff) * (int)(signed char)((b >> 24) & 0xff);
  return c;
#endif
}

__device__ __forceinline__ u32 packq(int q0, int q1, int q2, int q3) {
  return (u32)(q0 & 255) | ((u32)(q1 & 255) << 8) |
         ((u32)(q2 & 255) << 16) | ((u32)(q3 & 255) << 24);
}

__device__ __forceinline__ float sigm(float x) {
  return __builtin_amdgcn_rcpf(1.f + __expf(-x));
}
__device__ __forceinline__ float tanh_fast(float x) {
  float e = __expf(-2.f * fabsf(x));
  float r = (1.f - e) * __builtin_amdgcn_rcpf(1.f + e);
  return copysignf(r, x);
}

// ---------------------------------------------------------------------------
__global__ void prep_kernel(float* logits) {
  const int i = threadIdx.x + blockIdx.x * 1024;
  if (i < 4096) logits[i] = 0.f;
}

// ---------------------------------------------------------------------------
// Gx[t][R] = emb[sentence[t]] . W_R + bih_R + bhh_R   (R = dir*1024 + row)
__global__ __launch_bounds__(256) void gx_kernel(
    const int* __restrict__ sentence, const float* __restrict__ emb,
    const float* __restrict__ Wih_f, const float* __restrict__ Wih_b,
    const float* __restrict__ bih_f, const float* __restrict__ bhh_f,
    const float* __restrict__ bih_b, const float* __restrict__ bhh_b,
    __half* __restrict__ Gx)
{
  __shared__ float ws[32][260];
  const int r0 = blockIdx.x * 32;
  const int t0 = blockIdx.y * 32;
  const int tid = threadIdx.x;
  {
    const int c4 = (tid & 63) * 4;
    const int rA = tid >> 6;
    #pragma unroll
    for (int p = 0; p < 8; ++p) {
      const int rr = rA + p * 4;
      const int R = r0 + rr;
      const float* src = (R < 1024) ? (Wih_f + (size_t)R * 256 + c4)
                                    : (Wih_b + (size_t)(R - 1024) * 256 + c4);
      *(float4*)&ws[rr][c4] = *(const float4*)src;
    }
  }
  __syncthreads();
  const int ttb = tid >> 4, rgb = tid & 15;
  const int s0r = sentence[t0 + ttb];
  const int s1r = sentence[t0 + ttb + 16];
  const float* x0p = emb + (size_t)s0r * 256;
  const float* x1p = emb + (size_t)s1r * 256;
  float acc00 = 0, acc01 = 0, acc10 = 0, acc11 = 0;
  #pragma unroll 4
  for (int c4 = 0; c4 < 256; c4 += 4) {
    float4 x0 = *(const float4*)(x0p + c4);
    float4 x1 = *(const float4*)(x1p + c4);
    float4 w0 = *(const float4*)&ws[rgb][c4];
    float4 w1 = *(const float4*)&ws[rgb + 16][c4];
    acc00 += x0.x*w0.x + x0.y*w0.y + x0.z*w0.z + x0.w*w0.w;
    acc01 += x0.x*w1.x + x0.y*w1.y + x0.z*w1.z + x0.w*w1.w;
    acc10 += x1.x*w0.x + x1.y*w0.y + x1.z*w0.z + x1.w*w0.w;
    acc11 += x1.x*w1.x + x1.y*w1.y + x1.z*w1.z + x1.w*w1.w;
  }
  #pragma unroll
  for (int ri = 0; ri < 2; ++ri) {
    const int R = r0 + rgb + ri * 16;
    const int dir = R >> 10, grow = R & 1023;
    const float bias = dir ? (bih_b[grow] + bhh_b[grow])
                           : (bih_f[grow] + bhh_f[grow]);
    const float a0 = ri ? acc01 : acc00;
    const float a1 = ri ? acc11 : acc10;
    Gx[(size_t)(t0 + ttb) * 2048 + R]      = __float2half(a0 + bias);
    Gx[(size_t)(t0 + ttb + 16) * 2048 + R] = __float2half(a1 + bias);
  }
}

// ---------------------------------------------------------------------------
// Recurrence v2: 1 WG per direction (grid=2), 1024 threads, ZERO cross-WG sync.
// Whh int8 per-row-quantized in 64 VGPRs/thread. Lane layout within wave:
//   g = lane&15 (row group), c = lane>>4 (64-col chunk).
// Thread (wave w, lane l) owns rows r_k = 64w + 16k + g (k=0..3), cols 64c..64c+63.
// Per step: dot4 over local chunk, shfl_xor(16/32) combines the 4 chunks.
// h kept int8-packed in LDS; h history buffered fp16 in LDS, flushed /128 steps.
__global__ __launch_bounds__(1024, 4) void lstm_kernel(
    const float* __restrict__ Whh_f, const float* __restrict__ Whh_b,
    const float* __restrict__ h0, const float* __restrict__ c0,
    const __half* __restrict__ Gx, float* __restrict__ out_lstm)
{
  const int dir = blockIdx.x;
  const int tid = threadIdx.x;
  const int w = tid >> 6, l = tid & 63;
  const int g = l & 15, c = l >> 4;
  const float* Whh = dir ? Whh_b : Whh_f;

  __shared__ __align__(16) u32 hq[64];        // current h, int8 x256
  __shared__ float gates[1024];
  __shared__ __align__(16) u16 hist[128 * 256]; // 64 KB fp16 h history

  u32 w8[64];
  float fs0, fs1, fs2, fs3;
  {
    // quantize Whh rows (two passes to keep register pressure low)
    float fsk[4];
    #pragma unroll
    for (int k = 0; k < 4; ++k) {
      const int row = 64 * w + 16 * k + g;
      const float* wr = Whh + (size_t)row * 256 + 64 * c;
      float mx = 0.f;
      #pragma unroll
      for (int j = 0; j < 16; ++j) {
        float4 f = ((const float4*)wr)[j];
        mx = fmaxf(mx, fmaxf(fmaxf(fabsf(f.x), fabsf(f.y)),
                             fmaxf(fabsf(f.z), fabsf(f.w))));
      }
      mx = fmaxf(mx, __shfl_xor(mx, 16));
      mx = fmaxf(mx, __shfl_xor(mx, 32));
      const float inv = (mx > 0.f) ? (127.f / mx) : 0.f;
      fsk[k] = mx * (4.f / (127.f * 127.f));   // w-scale * h-scale
      #pragma unroll
      for (int j = 0; j < 16; ++j) {
        float4 f = ((const float4*)wr)[j];
        w8[16 * k + j] = packq((int)rintf(f.x * inv), (int)rintf(f.y * inv),
                               (int)rintf(f.z * inv), (int)rintf(f.w * inv));
      }
    }
    fs0 = fsk[0]; fs1 = fsk[1]; fs2 = fsk[2]; fs3 = fsk[3];
  }

  // init h (int8, scale 4/127 covers |h0| up to 4) and c
  float creg = 0.f;
  u16 p0 = 0, p1 = 0, p2 = 0, p3 = 0;   // Gx for current step (fp16 bits)
  u16 n0 = 0, n1 = 0, n2 = 0, n3 = 0;   // prefetched next step
  if (tid < 256) {
    int q = (int)rintf(h0[dir * 256 + tid] * 31.75f);
    q = max(-127, min(127, q));
    int q1 = __shfl_down(q, 1), q2 = __shfl_down(q, 2), q3 = __shfl_down(q, 3);
    if ((tid & 3) == 0) hq[tid >> 2] = packq(q, q1, q2, q3);
    creg = c0[dir * 256 + tid];
    const int t0i = dir ? (T_LEN - 1) : 0;
    const u16* gp = (const u16*)Gx + (size_t)t0i * 2048 + dir * 1024 + tid;
    p0 = gp[0]; p1 = gp[256]; p2 = gp[512]; p3 = gp[768];
  }
  __syncthreads();

  const uint4* hq4 = (const uint4*)hq;
  for (int s = 0; s < T_LEN; ++s) {
    // phase A ---------------------------------------------------------------
    if (tid < 256 && s + 1 < T_LEN) {   // prefetch next Gx; lands by barrier B
      const int tn = dir ? (T_LEN - 2 - s) : (s + 1);
      const u16* gp = (const u16*)Gx + (size_t)tn * 2048 + dir * 1024 + tid;
      n0 = gp[0]; n1 = gp[256]; n2 = gp[512]; n3 = gp[768];
    }
    u32 hu[16];
    *(uint4*)&hu[0]  = hq4[4 * c + 0];
    *(uint4*)&hu[4]  = hq4[4 * c + 1];
    *(uint4*)&hu[8]  = hq4[4 * c + 2];
    *(uint4*)&hu[12] = hq4[4 * c + 3];
    int a0 = 0, a1 = 0, a2 = 0, a3 = 0;
    #pragma unroll
    for (int j = 0; j < 16; ++j) {
      a0 = sdot4(w8[j],      hu[j], a0);
      a1 = sdot4(w8[16 + j], hu[j], a1);
      a2 = sdot4(w8[32 + j], hu[j], a2);
      a3 = sdot4(w8[48 + j], hu[j], a3);
    }
    a0 += __shfl_xor(a0, 16); a0 += __shfl_xor(a0, 32);
    a1 += __shfl_xor(a1, 16); a1 += __shfl_xor(a1, 32);
    a2 += __shfl_xor(a2, 16); a2 += __shfl_xor(a2, 32);
    a3 += __shfl_xor(a3, 16); a3 += __shfl_xor(a3, 32);
    if (c == 0) {
      gates[64 * w + g]      = (float)a0 * fs0;
      gates[64 * w + 16 + g] = (float)a1 * fs1;
      gates[64 * w + 32 + g] = (float)a2 * fs2;
      gates[64 * w + 48 + g] = (float)a3 * fs3;
    }
    __syncthreads();
    // phase C ---------------------------------------------------------------
    if (tid < 256) {
      const int d = tid;
      float gi = gates[d]       + __half2float(__ushort_as_half(p0));
      float gf = gates[256 + d] + __half2float(__ushort_as_half(p1));
      float gg = gates[512 + d] + __half2float(__ushort_as_half(p2));
      float go = gates[768 + d] + __half2float(__ushort_as_half(p3));
      p0 = n0; p1 = n1; p2 = n2; p3 = n3;
      const float iv = sigm(gi);
      const float fv = sigm(gf);
      const float gv = tanh_fast(gg);
      const float ov = sigm(go);
      creg = fv * creg + iv * gv;
      const float h = ov * tanh_fast(creg);
      hist[(s & 127) * 256 + d] = __half_as_ushort(__float2half(h));
      int q = (int)rintf(h * 31.75f);
      q = max(-127, min(127, q));
      int q1 = __shfl_down(q, 1), q2 = __shfl_down(q, 2), q3 = __shfl_down(q, 3);
      if ((d & 3) == 0) hq[d >> 2] = packq(q, q1, q2, q3);
    }
    __syncthreads();
    // flush h history every 128 steps --------------------------------------
    if ((s & 127) == 127) {
      const int sbase = s - 127;
      #pragma unroll
      for (int i = 0; i < 8; ++i) {
        const int v0 = (tid + i * 1024) * 4;
        const int step = v0 >> 8, d0 = v0 & 255;
        const int tt = sbase + step;
        const int t = dir ? (T_LEN - 1 - tt) : tt;
        uint2 hv = ((const uint2*)hist)[(step * 256 + d0) >> 2];
        float4 ov;
        ov.x = __half2float(__ushort_as_half((u16)(hv.x & 0xffff)));
        ov.y = __half2float(__ushort_as_half((u16)(hv.x >> 16)));
        ov.z = __half2float(__ushort_as_half((u16)(hv.y & 0xffff)));
        ov.w = __half2float(__ushort_as_half((u16)(hv.y >> 16)));
        *(float4*)&out_lstm[(size_t)t * 512 + dir * 256 + d0] = ov;
      }
      __syncthreads();
    }
  }
}

// ---------------------------------------------------------------------------
// logits[t] = sum_c tanh(out[t] @ w_omega)[c] * u_omega[c]
__global__ __launch_bounds__(256) void attn_kernel(
    const float* __restrict__ out_lstm, const float* __restrict__ w_omega,
    const float* __restrict__ u_omega, float* __restrict__ logits)
{
  __shared__ float bst[32][132];
  const int c0 = blockIdx.x * 32;
  const int t0 = blockIdx.y * 32;
  const int tid = threadIdx.x;
  const int ttb = tid >> 4, cgb = tid & 15;
  const float* a0p = out_lstm + (size_t)(t0 + ttb) * 512;
  const float* a1p = out_lstm + (size_t)(t0 + ttb + 16) * 512;
  float acc00 = 0, acc01 = 0, acc10 = 0, acc11 = 0;
  for (int kh = 0; kh < 4; ++kh) {
    __syncthreads();
    {
      const int cc = tid & 31;
      const int kA = tid >> 5;
      #pragma unroll
      for (int p = 0; p < 16; ++p) {
        const int kkx = kA + p * 8;
        bst[cc][kkx] = w_omega[(size_t)(kh * 128 + kkx) * 512 + c0 + cc];
      }
    }
    __syncthreads();
    #pragma unroll 4
    for (int k4 = 0; k4 < 128; k4 += 4) {
      float4 a0 = *(const float4*)(a0p + kh * 128 + k4);
      float4 a1 = *(const float4*)(a1p + kh * 128 + k4);
      float4 b0 = *(const float4*)&bst[cgb][k4];
      float4 b1 = *(const float4*)&bst[cgb + 16][k4];
      acc00 += a0.x*b0.x + a0.y*b0.y + a0.z*b0.z + a0.w*b0.w;
      acc01 += a0.x*b1.x + a0.y*b1.y + a0.z*b1.z + a0.w*b1.w;
      acc10 += a1.x*b0.x + a1.y*b0.y + a1.z*b0.z + a1.w*b0.w;
      acc11 += a1.x*b1.x + a1.y*b1.y + a1.z*b1.z + a1.w*b1.w;
    }
  }
  const float u0 = u_omega[c0 + cgb], u1 = u_omega[c0 + 16 + cgb];
  float s0 = tanh_fast(acc00) * u0 + tanh_fast(acc01) * u1;
  float s1 = tanh_fast(acc10) * u0 + tanh_fast(acc11) * u1;
  #pragma unroll
  for (int msk = 1; msk < 16; msk <<= 1) {
    s0 += __shfl_xor(s0, msk);
    s1 += __shfl_xor(s1, msk);
  }
  if (cgb == 0) {
    atomicAdd(&logits[t0 + ttb], s0);
    atomicAdd(&logits[t0 + ttb + 16], s1);
  }
}

// ---------------------------------------------------------------------------
__global__ __launch_bounds__(1024) void softmax_kernel(
    const float* __restrict__ logits, float* __restrict__ alphas)
{
  __shared__ float red[1024];
  const int tid = threadIdx.x;
  float l0 = logits[tid], l1 = logits[1024 + tid];
  float l2 = logits[2048 + tid], l3 = logits[3072 + tid];
  red[tid] = fmaxf(fmaxf(l0, l1), fmaxf(l2, l3));
  __syncthreads();
  for (int s = 512; s > 0; s >>= 1) {
    if (tid < s) red[tid] = fmaxf(red[tid], red[tid + s]);
    __syncthreads();
  }
  const float gm = red[0];
  __syncthreads();
  float e0 = __expf(l0 - gm), e1 = __expf(l1 - gm);
  float e2 = __expf(l2 - gm), e3 = __expf(l3 - gm);
  red[tid] = e0 + e1 + e2 + e3;
  __syncthreads();
  for (int s = 512; s > 0; s >>= 1) {
    if (tid < s) red[tid] += red[tid + s];
    __syncthreads();
  }
  const float inv = 1.0f / red[0];
  alphas[tid] = e0 * inv; alphas[1024 + tid] = e1 * inv;
  alphas[2048 + tid] = e2 * inv; alphas[3072 + tid] = e3 * inv;
}

// ---------------------------------------------------------------------------
__global__ __launch_bounds__(256) void feats_kernel(
    const float* __restrict__ out_lstm, const float* __restrict__ W_tag,
    const float* __restrict__ b_tag, const float* __restrict__ alphas,
    float* __restrict__ feats)
{
  __shared__ float wt[16][516];
  const int t0 = blockIdx.x * 16;
  const int tid = threadIdx.x;
  {
    const int k4 = (tid & 127) * 4;
    const int gA = tid >> 7;
    #pragma unroll
    for (int p = 0; p < 8; ++p) {
      const int tg = gA + p * 2;
      *(float4*)&wt[tg][k4] = *(const float4*)(W_tag + (size_t)tg * 512 + k4);
    }
  }
  __syncthreads();
  const int tt = tid >> 4, tg = tid & 15;
  const float* ap = out_lstm + (size_t)(t0 + tt) * 512;
  float acc = 0.f;
  #pragma unroll 4
  for (int k4 = 0; k4 < 512; k4 += 4) {
    float4 a = *(const float4*)(ap + k4);
    float4 b = *(const float4*)&wt[tg][k4];
    acc += a.x*b.x + a.y*b.y + a.z*b.z + a.w*b.w;
  }
  feats[(size_t)(t0 + tt) * 16 + tg] = acc * alphas[t0 + tt] + b_tag[tg];
}

// ---------------------------------------------------------------------------
__global__ __launch_bounds__(64) void viterbi_kernel(
    const float* __restrict__ feats, const float* __restrict__ trans,
    float* __restrict__ d_out)
{
  __shared__ __align__(16) float fv[16];
  __shared__ u32 bpw[T_LEN * 2];
  const int l = threadIdx.x;
  const int n = l & 15, pg = l >> 4;
  const float4 tr4 = *(const float4*)(trans + n * 16 + pg * 4);
  if (l < 16) fv[l] = (l == START_TAG) ? 0.f : NEG_VAL;
  float fcur = (l < 16) ? feats[l] : 0.f;
  __syncthreads();
  for (int t = 0; t < T_LEN; ++t) {
    float4 f4 = *(const float4*)&fv[pg * 4];
    float m = f4.x + tr4.x; int mi = pg * 4;
    float c;
    c = f4.y + tr4.y; if (c > m) { m = c; mi = pg * 4 + 1; }
    c = f4.z + tr4.z; if (c > m) { m = c; mi = pg * 4 + 2; }
    c = f4.w + tr4.w; if (c > m) { m = c; mi = pg * 4 + 3; }
    float om; int omi;
    om = __shfl_xor(m, 16); omi = __shfl_xor(mi, 16);
    if (om > m || (om == m && omi < mi)) { m = om; mi = omi; }
    om = __shfl_xor(m, 32); omi = __shfl_xor(mi, 32);
    if (om > m || (om == m && omi < mi)) { m = om; mi = omi; }
    float fnext = 0.f;
    if (l < 16 && t + 1 < T_LEN) fnext = feats[(t + 1) * 16 + l];
    u32 v = (l < 16) ? ((u32)mi << ((n & 7) * 4)) : 0u;
    v |= __shfl_xor(v, 1);
    v |= __shfl_xor(v, 2);
    v |= __shfl_xor(v, 4);
    if (l == 0) bpw[t * 2] = v;
    if (l == 8) bpw[t * 2 + 1] = v;
    if (l < 16) fv[l] = m + fcur;
    fcur = fnext;
    __syncthreads();
  }
  if (l < 16) {
    float m = fv[l] + trans[STOP_TAG * 16 + l];
    int mi = l;
    #pragma unroll
    for (int msk = 1; msk < 16; msk <<= 1) {
      float om = __shfl_xor(m, msk); int omi = __shfl_xor(mi, msk);
      if (om > m || (om == m && omi < mi)) { m = om; mi = omi; }
    }
    if (l == 0) {
      d_out[0] = m;
      int cur = mi;
      for (int t = T_LEN - 1; t >= 0; --t) {
        d_out[1 + t] = (float)cur;
        const u32 word = bpw[t * 2 + (cur >> 3)];
        cur = (int)((word >> ((cur & 7) * 4)) & 15u);
      }
    }
  }
}

// ---------------------------------------------------------------------------
extern "C" void kernel_launch(void* const* d_in, const int* in_sizes, int n_in,
                              void* d_out, int out_size, void* d_ws, size_t ws_size,
                              hipStream_t stream)
{
  const int*   sentence = (const int*)  d_in[0];
  const float* emb      = (const float*)d_in[1];
  const float* Wih_f    = (const float*)d_in[2];
  const float* Whh_f    = (const float*)d_in[3];
  const float* bih_f    = (const float*)d_in[4];
  const float* bhh_f    = (const float*)d_in[5];
  const float* Wih_b    = (const float*)d_in[6];
  const float* Whh_b    = (const float*)d_in[7];
  const float* bih_b    = (const float*)d_in[8];
  const float* bhh_b    = (const float*)d_in[9];
  const float* h0       = (const float*)d_in[10];
  const float* c0       = (const float*)d_in[11];
  const float* w_omega  = (const float*)d_in[12];
  const float* u_omega  = (const float*)d_in[13];
  const float* W_tag    = (const float*)d_in[14];
  const float* b_tag    = (const float*)d_in[15];
  const float* trans    = (const float*)d_in[16];

  char* ws = (char*)d_ws;
  __half* Gx      = (__half*)(ws + GX_OFF);
  float* out_lstm = (float*)(ws + OUT_OFF);
  float* logits   = (float*)(ws + LOGITS_OFF);
  float* alphas   = (float*)(ws + ALPHAS_OFF);
  float* feats    = (float*)(ws + FEATS_OFF);
  float* out      = (float*)d_out;

  hipLaunchKernelGGL(prep_kernel, dim3(4), dim3(1024), 0, stream, logits);
  hipLaunchKernelGGL(gx_kernel, dim3(64, 128), dim3(256), 0, stream,
                     sentence, emb, Wih_f, Wih_b, bih_f, bhh_f, bih_b, bhh_b, Gx);
  hipLaunchKernelGGL(lstm_kernel, dim3(2), dim3(1024), 0, stream,
                     Whh_f, Whh_b, h0, c0, Gx, out_lstm);
  hipLaunchKernelGGL(attn_kernel, dim3(16, 128), dim3(256), 0, stream,
                     out_lstm, w_omega, u_omega, logits);
  hipLaunchKernelGGL(softmax_kernel, dim3(1), dim3(1024), 0, stream, logits, alphas);
  hipLaunchKernelGGL(feats_kernel, dim3(256), dim3(256), 0, stream,
                     out_lstm, W_tag, b_tag, alphas, feats);
  hipLaunchKernelGGL(viterbi_kernel, dim3(1), dim3(64), 0, stream, feats, trans, out);
}

// Round 3
// 5459.083 us; speedup vs baseline: 1.8403x; 1.3438x over previous
//
#include <hip/hip_runtime.h>
#include <hip/hip_fp16.h>

#define T_LEN 4096
#define START_TAG 14
#define STOP_TAG 15
#define NEG_VAL -10000.0f

typedef unsigned int u32;
typedef unsigned short u16;
typedef unsigned long long u64;

// ---------- ws layout (bytes) ----------
#define GX_OFF      0u              // __half [4096][2048]  (dir*1024 + gate*256 + d)
#define OUT_OFF     16777216u       // float  [4096][512]
#define LOGITS_OFF  25165824u       // float  [4096]
#define ALPHAS_OFF  25182208u       // float  [4096]
#define FEATS_OFF   25198592u       // float  [4096][16]
#define CMAT_OFF    25460736u       // float  [128][16][16]
#define VIN_OFF     25591808u       // float  [128][16]
#define BP_OFF      25600000u       // u32    [4096][2]   (16 nibbles/step)
#define BMAP_OFF    25632768u       // u32    [128][16]
#define STAIL_OFF   25640960u       // u32    [128][16]
#define BEST_OFF    25649152u       // u32    [1]

__device__ __forceinline__ int sdot4(u32 a, u32 b, int c) {
#if __has_builtin(__builtin_amdgcn_sdot4)
  return __builtin_amdgcn_sdot4((int)a, (int)b, c, false);
#else
  c += (int)(signed char)(a & 0xff)         * (int)(signed char)(b & 0xff);
  c += (int)(signed char)((a >> 8) & 0xff)  * (int)(signed char)((b >> 8) & 0xff);
  c += (int)(signed char)((a >> 16) & 0xff) * (int)(signed char)((b >> 16) & 0xff);
  c += (int)(signed char)((a >> 24) & 0xff) * (int)(signed char)((b >> 24) & 0xff);
  return c;
#endif
}

__device__ __forceinline__ u32 packq(int q0, int q1, int q2, int q3) {
  return (u32)(q0 & 255) | ((u32)(q1 & 255) << 8) |
         ((u32)(q2 & 255) << 16) | ((u32)(q3 & 255) << 24);
}

__device__ __forceinline__ float tanh_fast(float x) {
  float e = __expf(-2.f * fabsf(x));
  float r = (1.f - e) * __builtin_amdgcn_rcpf(1.f + e);
  return copysignf(r, x);
}

// ---------------------------------------------------------------------------
__global__ void prep_kernel(float* logits) {
  const int i = threadIdx.x + blockIdx.x * 1024;
  if (i < 4096) logits[i] = 0.f;
}

// ---------------------------------------------------------------------------
// Gx[t][R] = emb[sentence[t]] . W_R + bih_R + bhh_R   (R = dir*1024 + gate*256 + d)
__global__ __launch_bounds__(256) void gx_kernel(
    const int* __restrict__ sentence, const float* __restrict__ emb,
    const float* __restrict__ Wih_f, const float* __restrict__ Wih_b,
    const float* __restrict__ bih_f, const float* __restrict__ bhh_f,
    const float* __restrict__ bih_b, const float* __restrict__ bhh_b,
    __half* __restrict__ Gx)
{
  __shared__ float ws[32][260];
  const int r0 = blockIdx.x * 32;
  const int t0 = blockIdx.y * 32;
  const int tid = threadIdx.x;
  {
    const int c4 = (tid & 63) * 4;
    const int rA = tid >> 6;
    #pragma unroll
    for (int p = 0; p < 8; ++p) {
      const int rr = rA + p * 4;
      const int R = r0 + rr;
      const float* src = (R < 1024) ? (Wih_f + (size_t)R * 256 + c4)
                                    : (Wih_b + (size_t)(R - 1024) * 256 + c4);
      *(float4*)&ws[rr][c4] = *(const float4*)src;
    }
  }
  __syncthreads();
  const int ttb = tid >> 4, rgb = tid & 15;
  const int s0r = sentence[t0 + ttb];
  const int s1r = sentence[t0 + ttb + 16];
  const float* x0p = emb + (size_t)s0r * 256;
  const float* x1p = emb + (size_t)s1r * 256;
  float acc00 = 0, acc01 = 0, acc10 = 0, acc11 = 0;
  #pragma unroll 4
  for (int c4 = 0; c4 < 256; c4 += 4) {
    float4 x0 = *(const float4*)(x0p + c4);
    float4 x1 = *(const float4*)(x1p + c4);
    float4 w0 = *(const float4*)&ws[rgb][c4];
    float4 w1 = *(const float4*)&ws[rgb + 16][c4];
    acc00 += x0.x*w0.x + x0.y*w0.y + x0.z*w0.z + x0.w*w0.w;
    acc01 += x0.x*w1.x + x0.y*w1.y + x0.z*w1.z + x0.w*w1.w;
    acc10 += x1.x*w0.x + x1.y*w0.y + x1.z*w0.z + x1.w*w0.w;
    acc11 += x1.x*w1.x + x1.y*w1.y + x1.z*w1.z + x1.w*w1.w;
  }
  #pragma unroll
  for (int ri = 0; ri < 2; ++ri) {
    const int R = r0 + rgb + ri * 16;
    const int dir = R >> 10, grow = R & 1023;
    const float bias = dir ? (bih_b[grow] + bhh_b[grow])
                           : (bih_f[grow] + bhh_f[grow]);
    const float a0 = ri ? acc01 : acc00;
    const float a1 = ri ? acc11 : acc10;
    Gx[(size_t)(t0 + ttb) * 2048 + R]      = __float2half(a0 + bias);
    Gx[(size_t)(t0 + ttb + 16) * 2048 + R] = __float2half(a1 + bias);
  }
}

// ---------------------------------------------------------------------------
// Recurrence v3: grid=2 (dir), 1024 threads. Thread = one Whh row (gate,d):
// wave w covers cols 16w..16w+15 x 4 gates (lane: gate=l>>4, col=(l&15)+16w).
// Full 256-wide int8 dot per thread via broadcast ds_read_b128 of h (no
// cross-lane reduction). Activation in phase A via sigm(x)=0.5(tanh(x/2)+1).
// Gate gather with 4 in-wave shuffles. ONE barrier/step (parity h buffer).
__global__ __launch_bounds__(1024, 4) void lstm_kernel(
    const float* __restrict__ Whh_f, const float* __restrict__ Whh_b,
    const float* __restrict__ h0, const float* __restrict__ c0,
    const __half* __restrict__ Gx, float* __restrict__ out_lstm)
{
  const int dir = blockIdx.x;
  const int tid = threadIdx.x;
  const int wv = tid >> 6, l = tid & 63;
  const int gate = l >> 4, d = (wv << 4) | (l & 15);
  const int row = gate * 256 + d;
  const float* Whh = dir ? Whh_b : Whh_f;

  __shared__ __align__(16) u32 hq[2][64];       // int8 h, parity double-buffer
  __shared__ __align__(16) u16 hist[128 * 256]; // 64 KB fp16 h history

  // ---- load + quantize own weight row (two passes; L2 serves pass 2) ----
  u32 w8[64];
  float fs;
  {
    const float4* wr = (const float4*)(Whh + (size_t)row * 256);
    float mx = 1e-10f;
    #pragma unroll 8
    for (int j = 0; j < 64; ++j) {
      float4 f = wr[j];
      mx = fmaxf(mx, fmaxf(fmaxf(fabsf(f.x), fabsf(f.y)),
                           fmaxf(fabsf(f.z), fabsf(f.w))));
    }
    const float qs = 127.f / mx;
    fs = mx * (1.f / (127.f * 32.f));   // w-scale * h-scale(1/32)
    #pragma unroll
    for (int j = 0; j < 64; ++j) {
      float4 f = wr[j];
      w8[j] = packq((int)rintf(f.x * qs), (int)rintf(f.y * qs),
                    (int)rintf(f.z * qs), (int)rintf(f.w * qs));
    }
  }

  // act = a*t + b with t = tanh(x*s): gate 2 -> tanh, else sigmoid
  const float s_arg = (gate == 2) ? 1.f : 0.5f;
  const float a_act = (gate == 2) ? 1.f : 0.5f;
  const float b_act = (gate == 2) ? 0.f : 0.5f;

  float creg = c0[dir * 256 + d];
  if (gate == 0) {
    float hv = h0[dir * 256 + d];
    int q = max(-127, min(127, (int)rintf(hv * 32.f)));
    ((signed char*)&hq[0][0])[d] = (signed char)q;
  }
  const u16* GxU = (const u16*)Gx;
  const int t0i = dir ? (T_LEN - 1) : 0;
  u16 gcur = GxU[(size_t)t0i * 2048 + dir * 1024 + row];
  __syncthreads();

  for (int s = 0; s < T_LEN; ++s) {
    u16 gnxt = 0;
    if (s + 1 < T_LEN) {   // prefetch next step's Gx
      const int tn = dir ? (T_LEN - 2 - s) : (s + 1);
      gnxt = GxU[(size_t)tn * 2048 + dir * 1024 + row];
    }
    // 256-col int8 dot, broadcast LDS reads, 4 interleaved chains
    const uint4* hp = (const uint4*)&hq[s & 1][0];
    int a0 = 0, a1 = 0, a2 = 0, a3 = 0;
    #pragma unroll
    for (int j = 0; j < 16; ++j) {
      uint4 hv = hp[j];
      a0 = sdot4(w8[4 * j + 0], hv.x, a0);
      a1 = sdot4(w8[4 * j + 1], hv.y, a1);
      a2 = sdot4(w8[4 * j + 2], hv.z, a2);
      a3 = sdot4(w8[4 * j + 3], hv.w, a3);
    }
    const int acc = (a0 + a1) + (a2 + a3);
    const float x = (float)acc * fs + __half2float(__ushort_as_half(gcur));
    gcur = gnxt;
    const float tv = tanh_fast(x * s_arg);
    const float act = __builtin_fmaf(tv, a_act, b_act);
    // gather the 4 gate activations of this column (in-wave)
    const int bl = l & 15;
    const float iv = __shfl(act, bl);
    const float fv = __shfl(act, bl + 16);
    const float gv = __shfl(act, bl + 32);
    const float ov = __shfl(act, bl + 48);
    creg = __builtin_fmaf(fv, creg, iv * gv);
    const float h = ov * tanh_fast(creg);
    if (gate == 0) {
      hist[(s & 127) * 256 + d] = __half_as_ushort(__float2half(h));
      int q = max(-127, min(127, (int)rintf(h * 32.f)));
      ((signed char*)&hq[(s + 1) & 1][0])[d] = (signed char)q;
    }
    __syncthreads();
    if ((s & 127) == 127) {   // flush fp16 history -> out_lstm
      const int sbase = s - 127;
      #pragma unroll
      for (int i = 0; i < 8; ++i) {
        const int v0 = (tid + i * 1024) * 4;
        const int step = v0 >> 8, d0 = v0 & 255;
        const int tt = sbase + step;
        const int tg = dir ? (T_LEN - 1 - tt) : tt;
        uint2 hv = ((const uint2*)hist)[(step * 256 + d0) >> 2];
        float4 ov4;
        ov4.x = __half2float(__ushort_as_half((u16)(hv.x & 0xffff)));
        ov4.y = __half2float(__ushort_as_half((u16)(hv.x >> 16)));
        ov4.z = __half2float(__ushort_as_half((u16)(hv.y & 0xffff)));
        ov4.w = __half2float(__ushort_as_half((u16)(hv.y >> 16)));
        *(float4*)&out_lstm[(size_t)tg * 512 + dir * 256 + d0] = ov4;
      }
      __syncthreads();
    }
  }
}

// ---------------------------------------------------------------------------
__global__ __launch_bounds__(256) void attn_kernel(
    const float* __restrict__ out_lstm, const float* __restrict__ w_omega,
    const float* __restrict__ u_omega, float* __restrict__ logits)
{
  __shared__ float bst[32][132];
  const int c0 = blockIdx.x * 32;
  const int t0 = blockIdx.y * 32;
  const int tid = threadIdx.x;
  const int ttb = tid >> 4, cgb = tid & 15;
  const float* a0p = out_lstm + (size_t)(t0 + ttb) * 512;
  const float* a1p = out_lstm + (size_t)(t0 + ttb + 16) * 512;
  float acc00 = 0, acc01 = 0, acc10 = 0, acc11 = 0;
  for (int kh = 0; kh < 4; ++kh) {
    __syncthreads();
    {
      const int cc = tid & 31;
      const int kA = tid >> 5;
      #pragma unroll
      for (int p = 0; p < 16; ++p) {
        const int kkx = kA + p * 8;
        bst[cc][kkx] = w_omega[(size_t)(kh * 128 + kkx) * 512 + c0 + cc];
      }
    }
    __syncthreads();
    #pragma unroll 4
    for (int k4 = 0; k4 < 128; k4 += 4) {
      float4 a0 = *(const float4*)(a0p + kh * 128 + k4);
      float4 a1 = *(const float4*)(a1p + kh * 128 + k4);
      float4 b0 = *(const float4*)&bst[cgb][k4];
      float4 b1 = *(const float4*)&bst[cgb + 16][k4];
      acc00 += a0.x*b0.x + a0.y*b0.y + a0.z*b0.z + a0.w*b0.w;
      acc01 += a0.x*b1.x + a0.y*b1.y + a0.z*b1.z + a0.w*b1.w;
      acc10 += a1.x*b0.x + a1.y*b0.y + a1.z*b0.z + a1.w*b0.w;
      acc11 += a1.x*b1.x + a1.y*b1.y + a1.z*b1.z + a1.w*b1.w;
    }
  }
  const float u0 = u_omega[c0 + cgb], u1 = u_omega[c0 + 16 + cgb];
  float s0 = tanh_fast(acc00) * u0 + tanh_fast(acc01) * u1;
  float s1 = tanh_fast(acc10) * u0 + tanh_fast(acc11) * u1;
  #pragma unroll
  for (int msk = 1; msk < 16; msk <<= 1) {
    s0 += __shfl_xor(s0, msk);
    s1 += __shfl_xor(s1, msk);
  }
  if (cgb == 0) {
    atomicAdd(&logits[t0 + ttb], s0);
    atomicAdd(&logits[t0 + ttb + 16], s1);
  }
}

// ---------------------------------------------------------------------------
__global__ __launch_bounds__(1024) void softmax_kernel(
    const float* __restrict__ logits, float* __restrict__ alphas)
{
  __shared__ float red[1024];
  const int tid = threadIdx.x;
  float l0 = logits[tid], l1 = logits[1024 + tid];
  float l2 = logits[2048 + tid], l3 = logits[3072 + tid];
  red[tid] = fmaxf(fmaxf(l0, l1), fmaxf(l2, l3));
  __syncthreads();
  for (int s = 512; s > 0; s >>= 1) {
    if (tid < s) red[tid] = fmaxf(red[tid], red[tid + s]);
    __syncthreads();
  }
  const float gm = red[0];
  __syncthreads();
  float e0 = __expf(l0 - gm), e1 = __expf(l1 - gm);
  float e2 = __expf(l2 - gm), e3 = __expf(l3 - gm);
  red[tid] = e0 + e1 + e2 + e3;
  __syncthreads();
  for (int s = 512; s > 0; s >>= 1) {
    if (tid < s) red[tid] += red[tid + s];
    __syncthreads();
  }
  const float inv = 1.0f / red[0];
  alphas[tid] = e0 * inv; alphas[1024 + tid] = e1 * inv;
  alphas[2048 + tid] = e2 * inv; alphas[3072 + tid] = e3 * inv;
}

// ---------------------------------------------------------------------------
__global__ __launch_bounds__(256) void feats_kernel(
    const float* __restrict__ out_lstm, const float* __restrict__ W_tag,
    const float* __restrict__ b_tag, const float* __restrict__ alphas,
    float* __restrict__ feats)
{
  __shared__ float wt[16][516];
  const int t0 = blockIdx.x * 16;
  const int tid = threadIdx.x;
  {
    const int k4 = (tid & 127) * 4;
    const int gA = tid >> 7;
    #pragma unroll
    for (int p = 0; p < 8; ++p) {
      const int tg = gA + p * 2;
      *(float4*)&wt[tg][k4] = *(const float4*)(W_tag + (size_t)tg * 512 + k4);
    }
  }
  __syncthreads();
  const int tt = tid >> 4, tg = tid & 15;
  const float* ap = out_lstm + (size_t)(t0 + tt) * 512;
  float acc = 0.f;
  #pragma unroll 4
  for (int k4 = 0; k4 < 512; k4 += 4) {
    float4 a = *(const float4*)(ap + k4);
    float4 b = *(const float4*)&wt[tg][k4];
    acc += a.x*b.x + a.y*b.y + a.z*b.z + a.w*b.w;
  }
  feats[(size_t)(t0 + tt) * 16 + tg] = acc * alphas[t0 + tt] + b_tag[tg];
}

// ---------------------------------------------------------------------------
// Viterbi phase 1: per 32-step block, composed max-plus matrix C_b.
// M_t[n][p] = trans[n][p] + feat[t][n];  C <- M_t (x) C.
__global__ __launch_bounds__(256) void vit_block_mats(
    const float* __restrict__ feats, const float* __restrict__ trans,
    float* __restrict__ Cmat)
{
  __shared__ float C[2][16][17];
  const int b = blockIdx.x;
  const int tid = threadIdx.x;
  const int n = tid >> 4, p = tid & 15;
  float tr[16];
  #pragma unroll
  for (int k = 0; k < 16; ++k) tr[k] = trans[n * 16 + k];
  const int t0 = b * 32;
  C[0][n][p] = tr[p] + feats[t0 * 16 + n];
  float fnext = feats[(t0 + 1) * 16 + n];
  __syncthreads();
  for (int s = 1; s < 32; ++s) {
    const float ft = fnext;
    if (s + 1 < 32) fnext = feats[(t0 + s + 1) * 16 + n];
    const int pr = (s - 1) & 1, cu = s & 1;
    float m = tr[0] + C[pr][0][p];
    #pragma unroll
    for (int k = 1; k < 16; ++k) m = fmaxf(m, tr[k] + C[pr][k][p]);
    C[cu][n][p] = m + ft;
    __syncthreads();
  }
  Cmat[b * 256 + n * 16 + p] = C[1][n][p];
}

// Viterbi phase 2: single-wave scan of 128 block matrices -> block-entry
// states v_in[b], terminal score and best tag.
__global__ __launch_bounds__(64) void vit_scan(
    const float* __restrict__ Cmat, const float* __restrict__ trans,
    float* __restrict__ v_in, float* __restrict__ d_out, u32* __restrict__ best_ws)
{
  const int l = threadIdx.x;
  const int n = l & 15, pg = l >> 4;
  float v = (n == START_TAG) ? 0.f : NEG_VAL;   // replicated across pg
  for (int b = 0; b < 128; ++b) {
    if (pg == 0) v_in[b * 16 + n] = v;
    float4 c4 = *(const float4*)&Cmat[b * 256 + n * 16 + pg * 4];
    float cand = c4.x + __shfl(v, pg * 4 + 0);
    cand = fmaxf(cand, c4.y + __shfl(v, pg * 4 + 1));
    cand = fmaxf(cand, c4.z + __shfl(v, pg * 4 + 2));
    cand = fmaxf(cand, c4.w + __shfl(v, pg * 4 + 3));
    cand = fmaxf(cand, __shfl_xor(cand, 16));
    cand = fmaxf(cand, __shfl_xor(cand, 32));
    v = cand;
  }
  float term = v + trans[STOP_TAG * 16 + n];
  int mi = n;
  #pragma unroll
  for (int msk = 1; msk < 16; msk <<= 1) {
    float om = __shfl_xor(term, msk); int omi = __shfl_xor(mi, msk);
    if (om > term || (om == term && omi < mi)) { term = om; mi = omi; }
  }
  if (l == 0) { d_out[0] = term; *best_ws = (u32)mi; }
}

// Viterbi phase 3: per-block stepwise recursion from v_in -> backpointers.
__global__ __launch_bounds__(64) void vit_bp(
    const float* __restrict__ feats, const float* __restrict__ trans,
    const float* __restrict__ v_in, u32* __restrict__ bp)
{
  const int b = blockIdx.x;
  const int l = threadIdx.x;
  const int n = l & 15, pg = l >> 4;
  const float4 tr4 = *(const float4*)&trans[n * 16 + pg * 4];
  float v = v_in[b * 16 + n];
  const int t0 = b * 32;
  float fcur = feats[t0 * 16 + n];
  for (int s = 0; s < 32; ++s) {
    const int t = t0 + s;
    float fnext = (s + 1 < 32) ? feats[(t + 1) * 16 + n] : 0.f;
    float f0 = __shfl(v, pg * 4 + 0), f1 = __shfl(v, pg * 4 + 1);
    float f2 = __shfl(v, pg * 4 + 2), f3 = __shfl(v, pg * 4 + 3);
    float m = f0 + tr4.x; int mi = pg * 4;
    float c;
    c = f1 + tr4.y; if (c > m) { m = c; mi = pg * 4 + 1; }
    c = f2 + tr4.z; if (c > m) { m = c; mi = pg * 4 + 2; }
    c = f3 + tr4.w; if (c > m) { m = c; mi = pg * 4 + 3; }
    float om; int omi;
    om = __shfl_xor(m, 16); omi = __shfl_xor(mi, 16);
    if (om > m || (om == m && omi < mi)) { m = om; mi = omi; }
    om = __shfl_xor(m, 32); omi = __shfl_xor(mi, 32);
    if (om > m || (om == m && omi < mi)) { m = om; mi = omi; }
    u32 w = (l < 16) ? ((u32)mi << ((n & 7) * 4)) : 0u;
    w |= __shfl_xor(w, 1); w |= __shfl_xor(w, 2); w |= __shfl_xor(w, 4);
    if (l == 0) bp[t * 2] = w;
    if (l == 8) bp[t * 2 + 1] = w;
    v = m + fcur;
    fcur = fnext;
  }
}

// Viterbi phase 4a: compose each block's 32 bp maps -> Bmap[b].
__global__ __launch_bounds__(64) void vit_bmap(
    const u32* __restrict__ bp, u32* __restrict__ Bmap)
{
  const int b = blockIdx.x;
  const int l = threadIdx.x;
  if (l >= 16) return;
  int t = b * 32 + 31;
  u32 lo = bp[t * 2], hi = bp[t * 2 + 1];
  int A = (int)(((l < 8 ? lo : hi) >> ((l & 7) * 4)) & 15u);
  for (t = b * 32 + 30; t >= b * 32; --t) {
    lo = bp[t * 2]; hi = bp[t * 2 + 1];
    A = (int)(((A < 8 ? lo : hi) >> ((A & 7) * 4)) & 15u);
  }
  Bmap[b * 16 + l] = (u32)A;
}

// Viterbi phase 4b: suffix-scan block maps -> Stail[b] = S_{b+1}.
__global__ __launch_bounds__(64) void vit_suffix(
    const u32* __restrict__ Bmap, u32* __restrict__ Stail)
{
  __shared__ u32 bm[2048];
  const int l = threadIdx.x;
  for (int i = l; i < 2048; i += 64) bm[i] = Bmap[i];
  __syncthreads();
  if (l < 16) {
    int S = l;   // identity = suffix past the end
    for (int b = 127; b >= 0; --b) {
      Stail[b * 16 + l] = (u32)S;
      S = (int)bm[b * 16 + S];
    }
  }
}

// Viterbi phase 4c: emit path[t] = F_{t+1}(best), walking each block down.
__global__ __launch_bounds__(64) void vit_emit(
    const u32* __restrict__ bp, const u32* __restrict__ Stail,
    const u32* __restrict__ best_ws, float* __restrict__ d_out)
{
  const int b = blockIdx.x;
  const int l = threadIdx.x;
  const int best = (int)*best_ws;
  int A = (l < 16) ? (int)Stail[b * 16 + l] : 0;
  for (int s = 31; s >= 0; --s) {
    const int t = b * 32 + s;
    const int pv = __shfl(A, best);
    if (l == 0) d_out[1 + t] = (float)pv;
    if (s > 0) {
      const u32 lo = bp[t * 2], hi = bp[t * 2 + 1];
      A = (int)(((A < 8 ? lo : hi) >> ((A & 7) * 4)) & 15u);
    }
  }
}

// ---------------------------------------------------------------------------
extern "C" void kernel_launch(void* const* d_in, const int* in_sizes, int n_in,
                              void* d_out, int out_size, void* d_ws, size_t ws_size,
                              hipStream_t stream)
{
  const int*   sentence = (const int*)  d_in[0];
  const float* emb      = (const float*)d_in[1];
  const float* Wih_f    = (const float*)d_in[2];
  const float* Whh_f    = (const float*)d_in[3];
  const float* bih_f    = (const float*)d_in[4];
  const float* bhh_f    = (const float*)d_in[5];
  const float* Wih_b    = (const float*)d_in[6];
  const float* Whh_b    = (const float*)d_in[7];
  const float* bih_b    = (const float*)d_in[8];
  const float* bhh_b    = (const float*)d_in[9];
  const float* h0       = (const float*)d_in[10];
  const float* c0       = (const float*)d_in[11];
  const float* w_omega  = (const float*)d_in[12];
  const float* u_omega  = (const float*)d_in[13];
  const float* W_tag    = (const float*)d_in[14];
  const float* b_tag    = (const float*)d_in[15];
  const float* trans    = (const float*)d_in[16];

  char* ws = (char*)d_ws;
  __half* Gx      = (__half*)(ws + GX_OFF);
  float* out_lstm = (float*)(ws + OUT_OFF);
  float* logits   = (float*)(ws + LOGITS_OFF);
  float* alphas   = (float*)(ws + ALPHAS_OFF);
  float* feats    = (float*)(ws + FEATS_OFF);
  float* Cmat     = (float*)(ws + CMAT_OFF);
  float* v_in     = (float*)(ws + VIN_OFF);
  u32*   bp       = (u32*)  (ws + BP_OFF);
  u32*   Bmap     = (u32*)  (ws + BMAP_OFF);
  u32*   Stail    = (u32*)  (ws + STAIL_OFF);
  u32*   best_ws  = (u32*)  (ws + BEST_OFF);
  float* out      = (float*)d_out;

  hipLaunchKernelGGL(prep_kernel, dim3(4), dim3(1024), 0, stream, logits);
  hipLaunchKernelGGL(gx_kernel, dim3(64, 128), dim3(256), 0, stream,
                     sentence, emb, Wih_f, Wih_b, bih_f, bhh_f, bih_b, bhh_b, Gx);
  hipLaunchKernelGGL(lstm_kernel, dim3(2), dim3(1024), 0, stream,
                     Whh_f, Whh_b, h0, c0, Gx, out_lstm);
  hipLaunchKernelGGL(attn_kernel, dim3(16, 128), dim3(256), 0, stream,
                     out_lstm, w_omega, u_omega, logits);
  hipLaunchKernelGGL(softmax_kernel, dim3(1), dim3(1024), 0, stream, logits, alphas);
  hipLaunchKernelGGL(feats_kernel, dim3(256), dim3(256), 0, stream,
                     out_lstm, W_tag, b_tag, alphas, feats);
  hipLaunchKernelGGL(vit_block_mats, dim3(128), dim3(256), 0, stream,
                     feats, trans, Cmat);
  hipLaunchKernelGGL(vit_scan, dim3(1), dim3(64), 0, stream,
                     Cmat, trans, v_in, out, best_ws);
  hipLaunchKernelGGL(vit_bp, dim3(128), dim3(64), 0, stream,
                     feats, trans, v_in, bp);
  hipLaunchKernelGGL(vit_bmap, dim3(128), dim3(64), 0, stream, bp, Bmap);
  hipLaunchKernelGGL(vit_suffix, dim3(1), dim3(64), 0, stream, Bmap, Stail);
  hipLaunchKernelGGL(vit_emit, dim3(128), dim3(64), 0, stream,
                     bp, Stail, best_ws, out);
}